// Round 10
// baseline (37237.424 us; speedup 1.0000x reference)
//
#include <hip/hip_runtime.h>
#include <math.h>

#define A_ 64
#define B_ 256
#define D_ 128
#define H_ 512
#define STOT 16384
#define NWG 32

// s_getreg immediate: id | offset<<6 | (width-1)<<11 ; HW_REG_XCC_ID = 20
#define XCC_GETREG_IMM (20 | (31 << 11))

// workspace layout (float offsets)
#define OFF_XT    0
#define N_XT      (A_*D_*B_)              // transposed input [t][k][b]
#define OFF_HT0   (OFF_XT + N_XT)         // encoder h ping  [j][b]
#define OFF_HT1   (OFF_HT0 + H_*B_)       // encoder h pong
#define OFF_CT    (OFF_HT1 + H_*B_)       // encoder c       [j][b]
#define OFF_HTAP  (OFF_CT + H_*B_)        // decoder h taps  [256][512]
#define OFF_HB64  (OFF_HTAP + B_*H_)      // tagged h [2][512] u64
#define OFF_CINIT (OFF_HB64 + 4*H_)       // decoder initial c [512]
#define OFF_ELECT (OFF_CINIT + H_)        // ints: [0..7] per-XCD counters, [8] winner

__device__ __forceinline__ float sigf(float x) {
  return __builtin_amdgcn_rcpf(1.0f + __expf(-x));
}
// tanh(x) = 1 - 2/(e^{2x}+1); exact at saturation
__device__ __forceinline__ float tanhfast(float x) {
  return 1.0f - 2.0f * __builtin_amdgcn_rcpf(__expf(2.0f * x) + 1.0f);
}

struct P8 { unsigned long long v0,v1,v2,v3,v4,v5,v6,v7; };

// 8 coalesced nt loads (64 lanes x 8B contiguous = 512B each), one wait.
// nt: no L1 allocation => no stale-L1 livelock; served by the XCD-shared L2.
// Only wave 0 of each WG polls (32 pollers, 128KB/round — round 7 proved
// all-wave polling saturates the XCD L2). "=&v" early-clobber mandatory.
__device__ __forceinline__ void poll8(const unsigned long long* p, P8& r) {
  asm volatile(
      "global_load_dwordx2 %0, %8, off nt\n\t"
      "global_load_dwordx2 %1, %8, off offset:512 nt\n\t"
      "global_load_dwordx2 %2, %8, off offset:1024 nt\n\t"
      "global_load_dwordx2 %3, %8, off offset:1536 nt\n\t"
      "global_load_dwordx2 %4, %8, off offset:2048 nt\n\t"
      "global_load_dwordx2 %5, %8, off offset:2560 nt\n\t"
      "global_load_dwordx2 %6, %8, off offset:3072 nt\n\t"
      "global_load_dwordx2 %7, %8, off offset:3584 nt\n\t"
      "s_waitcnt vmcnt(0)"
      : "=&v"(r.v0), "=&v"(r.v1), "=&v"(r.v2), "=&v"(r.v3),
        "=&v"(r.v4), "=&v"(r.v5), "=&v"(r.v6), "=&v"(r.v7)
      : "v"(p) : "memory");
}
// liveness fallback: L1 invalidate first (proven round 5/6/8). 1/64 spins.
__device__ __forceinline__ void poll8_inv(const unsigned long long* p, P8& r) {
  asm volatile(
      "buffer_inv sc0\n\t"
      "global_load_dwordx2 %0, %8, off nt\n\t"
      "global_load_dwordx2 %1, %8, off offset:512 nt\n\t"
      "global_load_dwordx2 %2, %8, off offset:1024 nt\n\t"
      "global_load_dwordx2 %3, %8, off offset:1536 nt\n\t"
      "global_load_dwordx2 %4, %8, off offset:2048 nt\n\t"
      "global_load_dwordx2 %5, %8, off offset:2560 nt\n\t"
      "global_load_dwordx2 %6, %8, off offset:3072 nt\n\t"
      "global_load_dwordx2 %7, %8, off offset:3584 nt\n\t"
      "s_waitcnt vmcnt(0)"
      : "=&v"(r.v0), "=&v"(r.v1), "=&v"(r.v2), "=&v"(r.v3),
        "=&v"(r.v4), "=&v"(r.v5), "=&v"(r.v6), "=&v"(r.v7)
      : "v"(p) : "memory");
}
// nt store: write-through, leaves a CLEAN L2 copy that nt polls hit.
// (Round 8's plain dirty store + nt evict-on-read polls ping-ponged every
// handshake line through HBM: FETCH 245MB / WRITE 262MB. This is the fix.)
__device__ __forceinline__ void store_nt(unsigned long long* p, unsigned long long v) {
  asm volatile("global_store_dwordx2 %0, %1, off nt" :: "v"(p), "v"(v) : "memory");
}

// ---------------------------------------------------------------------------
// init1: transpose input to XT[t][k][b], zero encoder h0/c0
// ---------------------------------------------------------------------------
__global__ void init1(const float* __restrict__ in0, float* __restrict__ ws) {
  float* XT  = ws + OFF_XT;
  float* HT0 = ws + OFF_HT0;
  float* CT  = ws + OFF_CT;
  int stride = gridDim.x * blockDim.x;
  for (int idx = blockIdx.x * blockDim.x + threadIdx.x; idx < N_XT; idx += stride) {
    int t = idx >> 15;
    int k = (idx >> 8) & 127;
    int b = idx & 255;
    XT[idx] = in0[t * (B_ * D_) + b * D_ + k];
    if (idx < H_ * B_) { HT0[idx] = 0.f; CT[idx] = 0.f; }
  }
}

// ---------------------------------------------------------------------------
// enc_step: one encoder LSTM timestep, fused GEMM (256x2048x640) + update.
// ---------------------------------------------------------------------------
__global__ __launch_bounds__(256) void enc_step(
    const float* __restrict__ XT, const float* __restrict__ Wih,
    const float* __restrict__ Whh, const float* __restrict__ bih,
    const float* __restrict__ bhh, const float* __restrict__ Hin,
    float* __restrict__ Hout, float* __restrict__ C, int t) {
  __shared__ float Wt[16 * 68];
  __shared__ float XHt[16 * 32];
  __shared__ float gs[64 * 33];
  const int tid = threadIdx.x;
  const int jt = blockIdx.x;
  const int bt = blockIdx.y;
  const int rr = tid >> 4;
  const int bb = tid & 15;

  float acc[4][2];
#pragma unroll
  for (int i = 0; i < 4; ++i) {
    int r = 4 * rr + i;
    int Row = ((r >> 4) << 9) + (jt << 4) + (r & 15);
    float bv = bih[Row] + bhh[Row];
    acc[i][0] = bv; acc[i][1] = bv;
  }

  for (int kt = 0; kt < 40; ++kt) {
    int k0 = kt << 4;
    __syncthreads();
#pragma unroll
    for (int e = 0; e < 4; ++e) {
      int idx = tid + (e << 8);
      int kk = idx & 15, r = idx >> 4;
      int Row = ((r >> 4) << 9) + (jt << 4) + (r & 15);
      int k = k0 + kk;
      float v = (k < D_) ? Wih[Row * D_ + k] : Whh[Row * H_ + (k - D_)];
      Wt[kk * 68 + r] = v;
    }
#pragma unroll
    for (int e = 0; e < 2; ++e) {
      int idx = tid + (e << 8);
      int kk = idx >> 5, b = idx & 31;
      int k = k0 + kk;
      int gb = (bt << 5) + b;
      float v = (k < D_) ? XT[(t * D_ + k) * B_ + gb] : Hin[(k - D_) * B_ + gb];
      XHt[kk * 32 + b] = v;
    }
    __syncthreads();
#pragma unroll
    for (int kk = 0; kk < 16; ++kk) {
      const float4 wv = *(const float4*)&Wt[kk * 68 + 4 * rr];
      const float2 xv = *(const float2*)&XHt[kk * 32 + 2 * bb];
      acc[0][0] += wv.x * xv.x; acc[0][1] += wv.x * xv.y;
      acc[1][0] += wv.y * xv.x; acc[1][1] += wv.y * xv.y;
      acc[2][0] += wv.z * xv.x; acc[2][1] += wv.z * xv.y;
      acc[3][0] += wv.w * xv.x; acc[3][1] += wv.w * xv.y;
    }
  }
  __syncthreads();
#pragma unroll
  for (int i = 0; i < 4; ++i) {
    gs[(4 * rr + i) * 33 + 2 * bb]     = acc[i][0];
    gs[(4 * rr + i) * 33 + 2 * bb + 1] = acc[i][1];
  }
  __syncthreads();
#pragma unroll
  for (int e = 0; e < 2; ++e) {
    int idx = tid + (e << 8);
    int jj = idx >> 5, b = idx & 31;
    int gb = (bt << 5) + b;
    float iv = gs[jj * 33 + b];
    float fv = gs[(16 + jj) * 33 + b];
    float gv = gs[(32 + jj) * 33 + b];
    float ov = gs[(48 + jj) * 33 + b];
    int addr = ((jt << 4) + jj) * B_ + gb;
    float c = C[addr];
    c = sigf(fv) * c + sigf(iv) * tanhf(gv);
    C[addr] = c;
    Hout[addr] = sigf(ov) * tanhf(c);
  }
}

// ---------------------------------------------------------------------------
// init2: seed tagged h (tag 0 in parity 1, invalid in parity 0), seed c,
// HTAP[0], reset election.
// ---------------------------------------------------------------------------
__global__ void init2(float* __restrict__ ws) {
  const float* Hfin = ws + OFF_HT0;   // after 64 steps final h lands in HT0
  const float* CT   = ws + OFF_CT;
  unsigned long long* HB = (unsigned long long*)(ws + OFF_HB64);
  float* CIN  = ws + OFF_CINIT;
  float* HTAP = ws + OFF_HTAP;
  int* EL     = (int*)(ws + OFF_ELECT);
  int j = threadIdx.x;                // 512 threads
  float hj = Hfin[j * B_ + 255];
  HB[H_ + j] = (unsigned long long)__float_as_uint(hj);  // tag 0, parity 1
  HB[j]      = 0xFFFFFFFF00000000ull;
  CIN[j]  = CT[j * B_ + 255];
  HTAP[j] = hj;
  if (j < 8) EL[j] = 0;
  if (j == 8) EL[8] = -1;             // winner xcd
}

// ---------------------------------------------------------------------------
// decoder (round-8 relay structure + round-6 nt publish):
// 32 WGs x 16 waves on one elected XCD. Wave u owns h-element e=16w+u
// (full K=640 register-resident: lane kk holds k in {kk+64j}).
// Wave 0 polls the 512 tagged global slots (payload rides the poll), relays
// h into LDS, raises an LDS parity flag; waves 1..15 spin on the flag (zero
// L2 traffic), read h from LDS. Every wave computes its element's 4 gates,
// butterfly-reduces in-wave, updates c, and lane 0 publishes the tagged u64
// via nt store (clean L2 copy -> nt polls hit L2; round 8's plain store
// caused an HBM ping-pong: FETCH 245MB/WRITE 262MB).
// NO __syncthreads in the loop; no fan-in, no wave0 reduce tail.
// Overwrite safety: a poller sees all 512 tags == s+2 only after every
// element's wave finished step s+1, which implies every CU consumed its
// step-s LDS copy and finished its step-s global reads.
// ---------------------------------------------------------------------------
__global__ __launch_bounds__(1024) void decoder(
    const float* __restrict__ in0, const float* __restrict__ Wih,
    const float* __restrict__ Whh, const float* __restrict__ bih,
    const float* __restrict__ bhh, float* __restrict__ ws) {
  unsigned long long* HB = (unsigned long long*)(ws + OFF_HB64);
  float* HTAP = ws + OFF_HTAP;
  const float* CIN = ws + OFF_CINIT;

  __shared__ float h_lds[2][H_];      // [parity][element]
  __shared__ int flag[2];             // step tag whose data is in h_lds[p]
  __shared__ int role;

  const int tid = threadIdx.x;

  // ---- election: first XCD to seat 32 WGs wins; its ranks 0..31 decode ----
  if (tid == 0) {
    unsigned xcc = ((unsigned)__builtin_amdgcn_s_getreg(XCC_GETREG_IMM)) & 7u;
    int* EL = (int*)(ws + OFF_ELECT);
    int r = __hip_atomic_fetch_add(&EL[xcc], 1, __ATOMIC_RELAXED,
                                   __HIP_MEMORY_SCOPE_AGENT);
    int myrole = -1;
    if (r < NWG) {
      if (r == NWG - 1) {
        int exp = -1;
        __hip_atomic_compare_exchange_strong(&EL[8], &exp, (int)xcc,
            __ATOMIC_RELAXED, __ATOMIC_RELAXED, __HIP_MEMORY_SCOPE_AGENT);
      }
      int wx;
      do {
        wx = __hip_atomic_load(&EL[8], __ATOMIC_RELAXED, __HIP_MEMORY_SCOPE_AGENT);
        if (wx == -1) __builtin_amdgcn_s_sleep(2);
      } while (wx == -1);
      if (wx == (int)xcc) myrole = r;
    }
    role = myrole;
  }
  __syncthreads();
  if (role < 0) return;               // uniform per WG
  const int w = role;

  const int u  = tid >> 6;            // wave index -> element
  const int kk = tid & 63;            // lane -> K-slice {kk + 64j}
  const int e  = (w << 4) + u;        // owned h-element

  // register-resident weights: wh[g][m] for k=kk+64m (h), wx[g][j] (x)
  float wh[4][8], wx[4][2], bias4[4];
#pragma unroll
  for (int g = 0; g < 4; ++g) {
    int Row = (g << 9) + e;
#pragma unroll
    for (int m = 0; m < 8; ++m) wh[g][m] = Whh[Row * H_ + kk + 64 * m];
    wx[g][0] = Wih[Row * D_ + kk];
    wx[g][1] = Wih[Row * D_ + kk + 64];
    bias4[g] = bih[Row] + bhh[Row];
  }
  float c = CIN[e];                   // replicated in all lanes (identical)

  if (tid < 2) flag[tid] = -1;
  __syncthreads();                    // pre-loop only

  for (int s = 0; s < STOT; ++s) {
    const int p = (s + 1) & 1;
    // x loads — independent of h; issued before the wait to overlap
    const int tt = s & 63;
    const int bc = 255 - (s >> 6);
    const float* xp = in0 + (tt * B_ + bc) * D_ + kk;
    float xv0 = xp[0];
    float xv1 = xp[64];

    float h0, h1, h2, h3, h4, h5, h6, h7;
    if (u == 0) {
      // ---- poller: wait for all 512 tags == s; payload rides the poll ----
      const unsigned long long* base = HB + (p << 9) + kk;
      P8 r;
      int spins = 0;
      for (;;) {
        if ((++spins & 63) == 0) poll8_inv(base, r); else poll8(base, r);
        const unsigned us = (unsigned)s;
        bool ok = (unsigned)(r.v0 >> 32) == us && (unsigned)(r.v1 >> 32) == us &&
                  (unsigned)(r.v2 >> 32) == us && (unsigned)(r.v3 >> 32) == us &&
                  (unsigned)(r.v4 >> 32) == us && (unsigned)(r.v5 >> 32) == us &&
                  (unsigned)(r.v6 >> 32) == us && (unsigned)(r.v7 >> 32) == us;
        if (__all(ok)) break;
      }
      h0 = __uint_as_float((unsigned)r.v0);
      h1 = __uint_as_float((unsigned)r.v1);
      h2 = __uint_as_float((unsigned)r.v2);
      h3 = __uint_as_float((unsigned)r.v3);
      h4 = __uint_as_float((unsigned)r.v4);
      h5 = __uint_as_float((unsigned)r.v5);
      h6 = __uint_as_float((unsigned)r.v6);
      h7 = __uint_as_float((unsigned)r.v7);
      // ---- relay to siblings: LDS data, then fence, then parity flag ----
      h_lds[p][kk]       = h0;
      h_lds[p][kk + 64]  = h1;
      h_lds[p][kk + 128] = h2;
      h_lds[p][kk + 192] = h3;
      h_lds[p][kk + 256] = h4;
      h_lds[p][kk + 320] = h5;
      h_lds[p][kk + 384] = h6;
      h_lds[p][kk + 448] = h7;
      __asm__ volatile("s_waitcnt lgkmcnt(0)" ::: "memory");
      if (kk == 0) *(volatile int*)&flag[p] = s;
    } else {
      // ---- consumer: spin on the LDS flag (no L2 traffic), read h -------
      while (*(volatile int*)&flag[p] != s) { }
      __asm__ volatile("" ::: "memory");   // no hoisting of h reads
      h0 = h_lds[p][kk];
      h1 = h_lds[p][kk + 64];
      h2 = h_lds[p][kk + 128];
      h3 = h_lds[p][kk + 192];
      h4 = h_lds[p][kk + 256];
      h5 = h_lds[p][kk + 320];
      h6 = h_lds[p][kk + 384];
      h7 = h_lds[p][kk + 448];
    }

    float a0, a1, a2, a3;
#define GATE(gi, dst)                                                          \
    dst = wx[gi][0] * xv0 + wx[gi][1] * xv1 + wh[gi][0] * h0 + wh[gi][1] * h1  \
        + wh[gi][2] * h2 + wh[gi][3] * h3 + wh[gi][4] * h4 + wh[gi][5] * h5    \
        + wh[gi][6] * h6 + wh[gi][7] * h7;
    GATE(0, a0) GATE(1, a1) GATE(2, a2) GATE(3, a3)
#undef GATE

    // 6-stage butterfly: all lanes end with full 640-K gate sums (bit-identical)
#pragma unroll
    for (int mask = 1; mask < 64; mask <<= 1) {
      a0 += __shfl_xor(a0, mask);
      a1 += __shfl_xor(a1, mask);
      a2 += __shfl_xor(a2, mask);
      a3 += __shfl_xor(a3, mask);
    }

    // cell update, redundantly in all 64 lanes (keeps c replicated)
    float iv = sigf(a0 + bias4[0]);
    float fv = sigf(a1 + bias4[1]);
    float gv = tanhfast(a2 + bias4[2]);
    float ov = sigf(a3 + bias4[3]);
    c = fv * c + iv * gv;
    float hn = ov * tanhfast(c);

    if (kk == 0) {
      if ((s & 63) == 63) {
        int q = (s >> 6) + 1;
        if (q < 256) HTAP[q * H_ + e] = hn;
      }
      // nt publish: write-through, clean L2 copy for the nt pollers
      store_nt(&HB[((s & 1) << 9) + e],
               ((unsigned long long)(unsigned)(s + 1) << 32) | __float_as_uint(hn));
    }
  }
}

// ---------------------------------------------------------------------------
// out_proj: outs[255-b] = Htap[255-b] @ lin_W^T + lin_b, broadcast over a.
// ---------------------------------------------------------------------------
__global__ __launch_bounds__(128) void out_proj(
    const float* __restrict__ ws, const float* __restrict__ linW,
    const float* __restrict__ linb, float* __restrict__ out) {
  const float* HTAP = ws + OFF_HTAP;
  __shared__ float hs[H_];
  const int b = blockIdx.x;
  const int i = 255 - b;
  const int d = threadIdx.x;
  *(float4*)&hs[4 * d] = *(const float4*)&HTAP[i * H_ + 4 * d];
  __syncthreads();
  float acc = linb[d];
#pragma unroll 8
  for (int k = 0; k < H_; k += 4) {
    float4 w4 = *(const float4*)&linW[d * H_ + k];
    acc += w4.x * hs[k] + w4.y * hs[k + 1] + w4.z * hs[k + 2] + w4.w * hs[k + 3];
  }
  for (int a = 0; a < A_; ++a)
    out[(a * B_ + b) * D_ + d] = acc;
}

// ---------------------------------------------------------------------------
extern "C" void kernel_launch(void* const* d_in, const int* in_sizes, int n_in,
                              void* d_out, int out_size, void* d_ws, size_t ws_size,
                              hipStream_t stream) {
  const float* in0  = (const float*)d_in[0];
  const float* eWih = (const float*)d_in[1];
  const float* eWhh = (const float*)d_in[2];
  const float* ebih = (const float*)d_in[3];
  const float* ebhh = (const float*)d_in[4];
  const float* dWih = (const float*)d_in[5];
  const float* dWhh = (const float*)d_in[6];
  const float* dbih = (const float*)d_in[7];
  const float* dbhh = (const float*)d_in[8];
  const float* linW = (const float*)d_in[9];
  const float* linb = (const float*)d_in[10];
  float* ws = (float*)d_ws;
  float* out = (float*)d_out;

  init1<<<2048, 256, 0, stream>>>(in0, ws);

  const float* XT = ws + OFF_XT;
  for (int t = 0; t < 64; ++t) {
    float* Hin  = ws + ((t & 1) ? OFF_HT1 : OFF_HT0);
    float* Hout = ws + ((t & 1) ? OFF_HT0 : OFF_HT1);
    enc_step<<<dim3(32, 8), 256, 0, stream>>>(XT, eWih, eWhh, ebih, ebhh,
                                              Hin, Hout, ws + OFF_CT, t);
  }
  init2<<<1, 512, 0, stream>>>(ws);
  decoder<<<256, 1024, 0, stream>>>(in0, dWih, dWhh, dbih, dbhh, ws);
  out_proj<<<256, 128, 0, stream>>>(ws, linW, linb, out);
}

// Round 11
// 23010.686 us; speedup vs baseline: 1.6183x; 1.6183x over previous
//
#include <hip/hip_runtime.h>
#include <math.h>

#define A_ 64
#define B_ 256
#define D_ 128
#define H_ 512
#define STOT 16384
#define NWG 32

// s_getreg immediate: id | offset<<6 | (width-1)<<11 ; HW_REG_XCC_ID = 20
#define XCC_GETREG_IMM (20 | (31 << 11))

// workspace layout (float offsets)
#define OFF_XT    0
#define N_XT      (A_*D_*B_)              // transposed input [t][k][b]
#define OFF_HT0   (OFF_XT + N_XT)         // encoder h ping  [j][b]
#define OFF_HT1   (OFF_HT0 + H_*B_)       // encoder h pong
#define OFF_CT    (OFF_HT1 + H_*B_)       // encoder c       [j][b]
#define OFF_HTAP  (OFF_CT + H_*B_)        // decoder h taps  [256][512]
#define OFF_HB64  (OFF_HTAP + B_*H_)      // tagged h [2][512] u64
#define OFF_CINIT (OFF_HB64 + 4*H_)       // decoder initial c [512]
#define OFF_ELECT (OFF_CINIT + H_)        // ints: [0..7] per-XCD counters, [8] winner

__device__ __forceinline__ float sigf(float x) {
  return __builtin_amdgcn_rcpf(1.0f + __expf(-x));
}
// tanh(x) = 1 - 2/(e^{2x}+1); exact at saturation
__device__ __forceinline__ float tanhfast(float x) {
  return 1.0f - 2.0f * __builtin_amdgcn_rcpf(__expf(2.0f * x) + 1.0f);
}

// nt load: no L1 allocation => never hits a stale L1 line; served by the
// XCD-shared L2. "=&v" early-clobber mandatory (round-3 lesson).
__device__ __forceinline__ unsigned long long load_nt(const unsigned long long* p) {
  unsigned long long v;
  asm volatile("global_load_dwordx2 %0, %1, off nt\n\ts_waitcnt vmcnt(0)"
               : "=&v"(v) : "v"(p) : "memory");
  return v;
}
// liveness fallback (round-5-proven): L1 invalidate + load. Used 1/64 spins.
__device__ __forceinline__ unsigned long long load_inv(const unsigned long long* p) {
  unsigned long long v;
  asm volatile("buffer_inv sc0\n\t"
               "global_load_dwordx2 %0, %1, off nt\n\ts_waitcnt vmcnt(0)"
               : "=&v"(v) : "v"(p) : "memory");
  return v;
}
// nt store: write-through leaving a CLEAN L2 copy that nt polls hit.
// Must be issued as ONE coalesced 128B burst per WG (16 contiguous u64 from
// wave0 lanes<16) — round 10's 512 scattered 8B nt stores caused 512MB of
// partial-line HBM write amplification.
__device__ __forceinline__ void store_nt(unsigned long long* p, unsigned long long v) {
  asm volatile("global_store_dwordx2 %0, %1, off nt" :: "v"(p), "v"(v) : "memory");
}

// ---------------------------------------------------------------------------
// init1: transpose input to XT[t][k][b], zero encoder h0/c0
// ---------------------------------------------------------------------------
__global__ void init1(const float* __restrict__ in0, float* __restrict__ ws) {
  float* XT  = ws + OFF_XT;
  float* HT0 = ws + OFF_HT0;
  float* CT  = ws + OFF_CT;
  int stride = gridDim.x * blockDim.x;
  for (int idx = blockIdx.x * blockDim.x + threadIdx.x; idx < N_XT; idx += stride) {
    int t = idx >> 15;
    int k = (idx >> 8) & 127;
    int b = idx & 255;
    XT[idx] = in0[t * (B_ * D_) + b * D_ + k];
    if (idx < H_ * B_) { HT0[idx] = 0.f; CT[idx] = 0.f; }
  }
}

// ---------------------------------------------------------------------------
// enc_step: one encoder LSTM timestep, fused GEMM (256x2048x640) + update.
// ---------------------------------------------------------------------------
__global__ __launch_bounds__(256) void enc_step(
    const float* __restrict__ XT, const float* __restrict__ Wih,
    const float* __restrict__ Whh, const float* __restrict__ bih,
    const float* __restrict__ bhh, const float* __restrict__ Hin,
    float* __restrict__ Hout, float* __restrict__ C, int t) {
  __shared__ float Wt[16 * 68];
  __shared__ float XHt[16 * 32];
  __shared__ float gs[64 * 33];
  const int tid = threadIdx.x;
  const int jt = blockIdx.x;
  const int bt = blockIdx.y;
  const int rr = tid >> 4;
  const int bb = tid & 15;

  float acc[4][2];
#pragma unroll
  for (int i = 0; i < 4; ++i) {
    int r = 4 * rr + i;
    int Row = ((r >> 4) << 9) + (jt << 4) + (r & 15);
    float bv = bih[Row] + bhh[Row];
    acc[i][0] = bv; acc[i][1] = bv;
  }

  for (int kt = 0; kt < 40; ++kt) {
    int k0 = kt << 4;
    __syncthreads();
#pragma unroll
    for (int e = 0; e < 4; ++e) {
      int idx = tid + (e << 8);
      int kk = idx & 15, r = idx >> 4;
      int Row = ((r >> 4) << 9) + (jt << 4) + (r & 15);
      int k = k0 + kk;
      float v = (k < D_) ? Wih[Row * D_ + k] : Whh[Row * H_ + (k - D_)];
      Wt[kk * 68 + r] = v;
    }
#pragma unroll
    for (int e = 0; e < 2; ++e) {
      int idx = tid + (e << 8);
      int kk = idx >> 5, b = idx & 31;
      int k = k0 + kk;
      int gb = (bt << 5) + b;
      float v = (k < D_) ? XT[(t * D_ + k) * B_ + gb] : Hin[(k - D_) * B_ + gb];
      XHt[kk * 32 + b] = v;
    }
    __syncthreads();
#pragma unroll
    for (int kk = 0; kk < 16; ++kk) {
      const float4 wv = *(const float4*)&Wt[kk * 68 + 4 * rr];
      const float2 xv = *(const float2*)&XHt[kk * 32 + 2 * bb];
      acc[0][0] += wv.x * xv.x; acc[0][1] += wv.x * xv.y;
      acc[1][0] += wv.y * xv.x; acc[1][1] += wv.y * xv.y;
      acc[2][0] += wv.z * xv.x; acc[2][1] += wv.z * xv.y;
      acc[3][0] += wv.w * xv.x; acc[3][1] += wv.w * xv.y;
    }
  }
  __syncthreads();
#pragma unroll
  for (int i = 0; i < 4; ++i) {
    gs[(4 * rr + i) * 33 + 2 * bb]     = acc[i][0];
    gs[(4 * rr + i) * 33 + 2 * bb + 1] = acc[i][1];
  }
  __syncthreads();
#pragma unroll
  for (int e = 0; e < 2; ++e) {
    int idx = tid + (e << 8);
    int jj = idx >> 5, b = idx & 31;
    int gb = (bt << 5) + b;
    float iv = gs[jj * 33 + b];
    float fv = gs[(16 + jj) * 33 + b];
    float gv = gs[(32 + jj) * 33 + b];
    float ov = gs[(48 + jj) * 33 + b];
    int addr = ((jt << 4) + jj) * B_ + gb;
    float c = C[addr];
    c = sigf(fv) * c + sigf(iv) * tanhf(gv);
    C[addr] = c;
    Hout[addr] = sigf(ov) * tanhf(c);
  }
}

// ---------------------------------------------------------------------------
// init2: seed tagged h (tag 0 in parity 1, invalid in parity 0), seed c,
// HTAP[0], reset election.
// ---------------------------------------------------------------------------
__global__ void init2(float* __restrict__ ws) {
  const float* Hfin = ws + OFF_HT0;   // after 64 steps final h lands in HT0
  const float* CT   = ws + OFF_CT;
  unsigned long long* HB = (unsigned long long*)(ws + OFF_HB64);
  float* CIN  = ws + OFF_CINIT;
  float* HTAP = ws + OFF_HTAP;
  int* EL     = (int*)(ws + OFF_ELECT);
  int j = threadIdx.x;                // 512 threads
  float hj = Hfin[j * B_ + 255];
  HB[H_ + j] = (unsigned long long)__float_as_uint(hj);  // tag 0, parity 1
  HB[j]      = 0xFFFFFFFF00000000ull;
  CIN[j]  = CT[j * B_ + 255];
  HTAP[j] = hj;
  if (j < 8) EL[j] = 0;
  if (j == 8) EL[8] = -1;             // winner xcd
}

// ---------------------------------------------------------------------------
// decoder (round-6 structure + CU-exclusivity + parked tail):
// 256 WGs launched; the 32 on one elected XCD run 16384 lock-step steps;
// others exit. Handshake = nt loads/stores via the shared XCD L2 (proven:
// FETCH 6.8MB). Each wave polls its own 32-slot slice, stages h to LDS,
// computes its K-partial; barrier 1; wave0 reduces + cell-update + ONE
// coalesced 128B nt publish; barrier 2 parks siblings during the tail
// (round 10 showed hot-spinning siblings steal the CU's issue slots).
// NEW: ~92KB LDS pad forces 1 WG/CU, so the 32 elected WGs always sit on 32
// distinct CUs — round 6's 50-60ms replays are the 2-WGs-on-one-CU
// collision (16+16 hot waves on 4 SIMDs ~2.5x the lock-step period).
// ---------------------------------------------------------------------------
__global__ __launch_bounds__(1024) void decoder(
    const float* __restrict__ in0, const float* __restrict__ Wih,
    const float* __restrict__ Whh, const float* __restrict__ bih,
    const float* __restrict__ bhh, float* __restrict__ ws) {
  unsigned long long* HB = (unsigned long long*)(ws + OFF_HB64);
  float* HTAP = ws + OFF_HTAP;
  const float* CIN = ws + OFF_CINIT;

  __shared__ float part[2][16 * 64];  // [parity][wave][row]
  __shared__ float hstage[H_];        // wave-private 32-float chunks
  __shared__ int role;
  __shared__ unsigned long long pad_lds[11520];  // 92KB: occupancy clamp -> 1 WG/CU

  const int tid = threadIdx.x;
  if (tid == 0) ((volatile unsigned long long*)pad_lds)[0] = 0;  // keep pad live

  // ---- election: first XCD to seat 32 WGs wins; its ranks 0..31 decode ----
  if (tid == 0) {
    unsigned xcc = ((unsigned)__builtin_amdgcn_s_getreg(XCC_GETREG_IMM)) & 7u;
    int* EL = (int*)(ws + OFF_ELECT);
    int r = __hip_atomic_fetch_add(&EL[xcc], 1, __ATOMIC_RELAXED,
                                   __HIP_MEMORY_SCOPE_AGENT);
    int myrole = -1;
    if (r < NWG) {
      if (r == NWG - 1) {
        int exp = -1;
        __hip_atomic_compare_exchange_strong(&EL[8], &exp, (int)xcc,
            __ATOMIC_RELAXED, __ATOMIC_RELAXED, __HIP_MEMORY_SCOPE_AGENT);
      }
      int wx;
      do {
        wx = __hip_atomic_load(&EL[8], __ATOMIC_RELAXED, __HIP_MEMORY_SCOPE_AGENT);
        if (wx == -1) __builtin_amdgcn_s_sleep(2);
      } while (wx == -1);
      if (wx == (int)xcc) myrole = r;
    }
    role = myrole;
  }
  __syncthreads();
  if (role < 0) return;               // uniform per WG
  const int w = role;

  const int v = tid >> 6;             // wave -> k-chunk [32v, 32v+32)
  const int l = tid & 63;             // lane -> local gate row
  const int R = ((l >> 4) << 9) + (w << 4) + (l & 15);  // global gate row

  float4 wa[8];
#pragma unroll
  for (int k = 0; k < 8; ++k)
    wa[k] = *(const float4*)&Whh[R * H_ + (v << 5) + 4 * k];
  float4 wx0 = *(const float4*)&Wih[R * D_ + (v << 3)];
  float4 wx1 = *(const float4*)&Wih[R * D_ + (v << 3) + 4];

  float bias = 0.f, c = 0.f;
  if (v == 0) {                       // wave 0 holds bias (per row) and c
    bias = bih[R] + bhh[R];
    if (l < 16) c = CIN[(w << 4) + l];
  }

  const int pe = (v << 5) + (l & 31); // polled element (2 lanes per element)

  for (int s = 0; s < STOT; ++s) {
    // x loads — independent of h, issued before the poll to overlap
    const int tt = s & 63;
    const int bc = 255 - (s >> 6);
    const float* xp = in0 + (tt * B_ + bc) * D_ + (v << 3);
    float4 x0 = *(const float4*)xp;
    float4 x1 = *(const float4*)(xp + 4);

    // poll h_{s-1}: nt loads from the shared L2; inv fallback 1/64 spins
    unsigned long long* slot = &HB[(((s + 1) & 1) << 9) + pe];
    unsigned long long pk;
    int spins = 0;
    for (;;) {
      pk = ((++spins & 63) == 0) ? load_inv(slot) : load_nt(slot);
      if (__all((unsigned)(pk >> 32) == (unsigned)s)) break;
    }
    if (l < 32) hstage[pe] = __uint_as_float((unsigned)pk);
    // intra-wave LDS dependency only: compiler's lgkmcnt wait suffices.

    float p = wx0.x * x0.x + wx0.y * x0.y + wx0.z * x0.z + wx0.w * x0.w
            + wx1.x * x1.x + wx1.y * x1.y + wx1.z * x1.z + wx1.w * x1.w;

    const float4* hp = (const float4*)&hstage[v << 5];
#pragma unroll
    for (int k = 0; k < 8; ++k) {
      float4 h4 = hp[k];                  // wave-uniform address: LDS broadcast
      p += wa[k].x * h4.x + wa[k].y * h4.y + wa[k].z * h4.z + wa[k].w * h4.w;
    }
    part[s & 1][(v << 6) + l] = p;
    __syncthreads();                      // barrier 1: partials ready

    if (v == 0) {
      float g = bias;
#pragma unroll
      for (int j = 0; j < 16; ++j) g += part[s & 1][(j << 6) + l];
      const int e = l & 15;
      float vi = __shfl(g, e);
      float vf = __shfl(g, e + 16);
      float vg = __shfl(g, e + 32);
      float vo = __shfl(g, e + 48);
      if (l < 16) {
        c = sigf(vf) * c + sigf(vi) * tanhfast(vg);
        float hn = sigf(vo) * tanhfast(c);
        if ((s & 63) == 63) {
          int q = (s >> 6) + 1;
          if (q < 256) HTAP[q * H_ + (w << 4) + l] = hn;
        }
        store_nt(&HB[((s & 1) << 9) + (w << 4) + l],
                 ((unsigned long long)(unsigned)(s + 1) << 32) | __float_as_uint(hn));
      }
    }
    __syncthreads();                      // barrier 2: park siblings during tail
  }
}

// ---------------------------------------------------------------------------
// out_proj: outs[255-b] = Htap[255-b] @ lin_W^T + lin_b, broadcast over a.
// ---------------------------------------------------------------------------
__global__ __launch_bounds__(128) void out_proj(
    const float* __restrict__ ws, const float* __restrict__ linW,
    const float* __restrict__ linb, float* __restrict__ out) {
  const float* HTAP = ws + OFF_HTAP;
  __shared__ float hs[H_];
  const int b = blockIdx.x;
  const int i = 255 - b;
  const int d = threadIdx.x;
  *(float4*)&hs[4 * d] = *(const float4*)&HTAP[i * H_ + 4 * d];
  __syncthreads();
  float acc = linb[d];
#pragma unroll 8
  for (int k = 0; k < H_; k += 4) {
    float4 w4 = *(const float4*)&linW[d * H_ + k];
    acc += w4.x * hs[k] + w4.y * hs[k + 1] + w4.z * hs[k + 2] + w4.w * hs[k + 3];
  }
  for (int a = 0; a < A_; ++a)
    out[(a * B_ + b) * D_ + d] = acc;
}

// ---------------------------------------------------------------------------
extern "C" void kernel_launch(void* const* d_in, const int* in_sizes, int n_in,
                              void* d_out, int out_size, void* d_ws, size_t ws_size,
                              hipStream_t stream) {
  const float* in0  = (const float*)d_in[0];
  const float* eWih = (const float*)d_in[1];
  const float* eWhh = (const float*)d_in[2];
  const float* ebih = (const float*)d_in[3];
  const float* ebhh = (const float*)d_in[4];
  const float* dWih = (const float*)d_in[5];
  const float* dWhh = (const float*)d_in[6];
  const float* dbih = (const float*)d_in[7];
  const float* dbhh = (const float*)d_in[8];
  const float* linW = (const float*)d_in[9];
  const float* linb = (const float*)d_in[10];
  float* ws = (float*)d_ws;
  float* out = (float*)d_out;

  init1<<<2048, 256, 0, stream>>>(in0, ws);

  const float* XT = ws + OFF_XT;
  for (int t = 0; t < 64; ++t) {
    float* Hin  = ws + ((t & 1) ? OFF_HT1 : OFF_HT0);
    float* Hout = ws + ((t & 1) ? OFF_HT0 : OFF_HT1);
    enc_step<<<dim3(32, 8), 256, 0, stream>>>(XT, eWih, eWhh, ebih, ebhh,
                                              Hin, Hout, ws + OFF_CT, t);
  }
  init2<<<1, 512, 0, stream>>>(ws);
  decoder<<<256, 1024, 0, stream>>>(in0, dWih, dWhh, dbih, dbhh, ws);
  out_proj<<<256, 128, 0, stream>>>(ws, linW, linb, out);
}